// Round 5
// baseline (7558.511 us; speedup 1.0000x reference)
//
#include <hip/hip_runtime.h>
#include <math.h>
#include <cstddef>

#define N_PTS 131072
#define SDIM  512
#define D1    513

static constexpr int NITER = 100;
static constexpr int BLK   = 512;            // 8 waves / block
static constexpr int GRID  = 512;            // 2 blocks / CU
static constexpr int WPB   = BLK / 64;       // 8 waves per block
static constexpr int NW    = GRID * WPB;     // 4096 waves
static constexpr int NPAIR = N_PTS / 2;      // 65536 row-pairs
static constexpr int PPW   = NPAIR / NW;     // 16 pairs per wave

struct Ws {
  unsigned int ticket;
  unsigned int pad[3];
  double colsum[514];          // [0..511] spatial, [512] t-sum, [513] cc-sum
  double part[514][GRID];      // column-major per-block partials
  float  mean[513];            // [0] = time coordinate
};

// ---------------- streaming kernel: partials only, no cross-block sync ----------------
template<bool INIT>
__global__ __launch_bounds__(BLK, 4)
void big_kernel(const float* __restrict__ data, Ws* __restrict__ ws, int rev)
{
  const int l    = threadIdx.x & 63;
  const int sl   = l & 31;       // lane within half
  const int half = l >> 5;       // 0: even row of pair, 1: odd row
  const int wid  = threadIdx.x >> 6;
  const int gw   = blockIdx.x * WPB + wid;   // 0..NW-1

  float  m0 = 0.f;
  float4 mk0 = {0,0,0,0}, mk1 = {0,0,0,0}, mk2 = {0,0,0,0}, mk3 = {0,0,0,0};
  if constexpr (!INIT) {
    m0 = ws->mean[0];
    const float4* mp = (const float4*)(ws->mean + 1);
    mk0 = mp[0*32 + sl]; mk1 = mp[1*32 + sl];
    mk2 = mp[2*32 + sl]; mk3 = mp[3*32 + sl];
  }

  // 16 f64 accumulators per lane; lane covers cols (j*32+sl)*4 + i
  double acc[4][4] = {};
  double acc_t = 0.0, acc_cc = 0.0;

  const int p0 = gw * PPW;

  float4 buf[3][4];   // rolling 3-deep pipeline (fully unrolled -> registers)

  auto LOADP = [&](float4* b, int p) {
    int pr = rev ? (NPAIR - 1 - p) : p;
    const float4* base = (const float4*)(data + (size_t)(2 * pr + half) * SDIM);
    b[0] = base[0*32 + sl]; b[1] = base[1*32 + sl];
    b[2] = base[2*32 + sl]; b[3] = base[3*32 + sl];
  };

  LOADP(buf[0], p0 + 0);
  LOADP(buf[1], p0 + 1);

  #pragma unroll
  for (int k = 0; k < PPW; ++k) {
    if (k + 2 < PPW) LOADP(buf[(k + 2) % 3], p0 + k + 2);
    const float4* c = buf[k % 3];

    // tree-shaped per-lane partial sums (shorter dependent chains)
    float sqa = c[0].x * c[0].x;
    sqa = fmaf(c[0].y, c[0].y, sqa); sqa = fmaf(c[0].z, c[0].z, sqa); sqa = fmaf(c[0].w, c[0].w, sqa);
    sqa = fmaf(c[1].x, c[1].x, sqa); sqa = fmaf(c[1].y, c[1].y, sqa);
    sqa = fmaf(c[1].z, c[1].z, sqa); sqa = fmaf(c[1].w, c[1].w, sqa);
    float sqb = c[2].x * c[2].x;
    sqb = fmaf(c[2].y, c[2].y, sqb); sqb = fmaf(c[2].z, c[2].z, sqb); sqb = fmaf(c[2].w, c[2].w, sqb);
    sqb = fmaf(c[3].x, c[3].x, sqb); sqb = fmaf(c[3].y, c[3].y, sqb);
    sqb = fmaf(c[3].z, c[3].z, sqb); sqb = fmaf(c[3].w, c[3].w, sqb);
    float sq = sqa + sqb;

    float dot = 0.f;
    if constexpr (!INIT) {
      float da = c[0].x * mk0.x;
      da = fmaf(c[0].y, mk0.y, da); da = fmaf(c[0].z, mk0.z, da); da = fmaf(c[0].w, mk0.w, da);
      da = fmaf(c[1].x, mk1.x, da); da = fmaf(c[1].y, mk1.y, da);
      da = fmaf(c[1].z, mk1.z, da); da = fmaf(c[1].w, mk1.w, da);
      float db = c[2].x * mk2.x;
      db = fmaf(c[2].y, mk2.y, db); db = fmaf(c[2].z, mk2.z, db); db = fmaf(c[2].w, mk2.w, db);
      db = fmaf(c[3].x, mk3.x, db); db = fmaf(c[3].y, mk3.y, db);
      db = fmaf(c[3].z, mk3.z, db); db = fmaf(c[3].w, mk3.w, db);
      dot = da + db;
    }

    // 5-level butterfly, stays within each 32-lane half
    #pragma unroll
    for (int m = 1; m < 32; m <<= 1) {
      sq += __shfl_xor(sq, m);
      if constexpr (!INIT) dot += __shfl_xor(dot, m);
    }

    float t = sqrtf(1.0f + sq);
    float w;
    if constexpr (INIT) {
      w = 1.0f;
    } else {
      float a = fmaf(m0, t, -dot);        // -mdot(mean, p)
      float x = fmaxf(a, 1.0f + 1e-5f);
      float s = sqrtf(fmaf(x, x, -1.0f)); // sinh(d)
      float d = logf(x + s);              // arccosh(x)
      w = d / s;                          // d / sinh(d)
      if (sl == 0) acc_cc = fma((double)w, (double)x, acc_cc);
    }
    if (sl == 0) acc_t = fma((double)w, (double)t, acc_t);

    double wd = (double)w;
    #pragma unroll
    for (int j = 0; j < 4; ++j) {
      acc[j][0] = fma(wd, (double)c[j].x, acc[j][0]);
      acc[j][1] = fma(wd, (double)c[j].y, acc[j][1]);
      acc[j][2] = fma(wd, (double)c[j].z, acc[j][2]);
      acc[j][3] = fma(wd, (double)c[j].w, acc[j][3]);
    }
  }

  // merge the two halves (same column sets): xor-32 shuffle on f64 accs
  #pragma unroll
  for (int j = 0; j < 4; ++j) {
    #pragma unroll
    for (int i = 0; i < 4; ++i) acc[j][i] += __shfl_xor(acc[j][i], 32);
  }
  acc_t  += __shfl_xor(acc_t, 32);
  acc_cc += __shfl_xor(acc_cc, 32);

  __shared__ double s_red[WPB][514];
  if (half == 0) {
    #pragma unroll
    for (int j = 0; j < 4; ++j) {
      #pragma unroll
      for (int i = 0; i < 4; ++i) s_red[wid][(j*32 + sl)*4 + i] = acc[j][i];
    }
  }
  if (l == 0) { s_red[wid][512] = acc_t; s_red[wid][513] = acc_cc; }
  __syncthreads();

  for (int cc2 = threadIdx.x; cc2 < 514; cc2 += BLK) {
    double s = 0.0;
    #pragma unroll
    for (int w2 = 0; w2 < WPB; ++w2) s += s_red[w2][cc2];
    ws->part[cc2][blockIdx.x] = s;
  }
}

// ---------------- finalize (device): one wave does the exp-map update ----------------
template<bool INIT>
__device__ void finalize_wave(Ws* __restrict__ ws, int l)
{
  double sv[9];
  #pragma unroll
  for (int q = 0; q < 9; ++q) {
    int c = q * 64 + l;
    sv[q] = 0.0;
    if (c < D1) sv[q] = ws->colsum[(c == 0) ? 512 : (c - 1)];
  }

  if constexpr (INIT) {
    double r[9]; double s2 = 0.0;
    #pragma unroll
    for (int q = 0; q < 9; ++q) {
      int c = q * 64 + l;
      r[q] = 0.0;
      if (c < D1) { r[q] = sv[q] / (double)N_PTS; s2 += r[q] * r[q]; }
    }
    #pragma unroll
    for (int m = 1; m < 64; m <<= 1) s2 += __shfl_xor(s2, m);
    double r0 = __shfl(r[0], 0);
    double inv = 1.0 / sqrt(fabs(s2 - 2.0 * r0 * r0));
    #pragma unroll
    for (int q = 0; q < 9; ++q) {
      int c = q * 64 + l;
      if (c < D1) ws->mean[c] = (float)(r[q] * inv);
    }
  } else {
    double cc = ws->colsum[513];
    double mv[9], yv[9]; double sy = 0.0;
    #pragma unroll
    for (int q = 0; q < 9; ++q) {
      int c = q * 64 + l;
      mv[q] = 0.0; yv[q] = 0.0;
      if (c < D1) {
        double m = (double)ws->mean[c];
        double y = 0.02 * (sv[q] - cc * m) / (double)N_PTS;  // y = -R*g, R=0.01
        mv[q] = m; yv[q] = y;
        sy += y * y;
      }
    }
    #pragma unroll
    for (int m = 1; m < 64; m <<= 1) sy += __shfl_xor(sy, m);
    double y0 = __shfl(yv[0], 0);
    double n = sqrt(fabs(sy - 2.0 * y0 * y0));
    n = fmax(n, 1e-5);
    double ch = cosh(n);
    double sn = (n < 1e-4) ? (1.0 + n * n / 6.0) : (sinh(n) / n);
    double nm[9]; double s2 = 0.0;
    #pragma unroll
    for (int q = 0; q < 9; ++q) {
      int c = q * 64 + l;
      nm[q] = 0.0;
      if (c < D1) { nm[q] = ch * mv[q] + sn * yv[q]; s2 += nm[q] * nm[q]; }
    }
    #pragma unroll
    for (int m = 1; m < 64; m <<= 1) s2 += __shfl_xor(s2, m);
    double m0n = __shfl(nm[0], 0);
    double inv = 1.0 / sqrt(fabs(s2 - 2.0 * m0n * m0n));
    #pragma unroll
    for (int q = 0; q < 9; ++q) {
      int c = q * 64 + l;
      if (c < D1) ws->mean[c] = (float)(nm[q] * inv);
    }
  }
}

// ---------------- per-column reduce + fused finalize (ticketed last block) ----------------
template<bool INIT>
__global__ __launch_bounds__(64)
void colreduce_kernel(Ws* __restrict__ ws)
{
  const int c = blockIdx.x;       // 0..513
  const int l = threadIdx.x;
  const double* col = ws->part[c];
  double s = 0.0;
  #pragma unroll
  for (int k = 0; k < GRID / 64; ++k) s += col[l + 64 * k];
  #pragma unroll
  for (int m = 1; m < 64; m <<= 1) s += __shfl_xor(s, m);
  if (l == 0) ws->colsum[c] = s;

  // ticket: last block to finish runs the exp-map update
  __shared__ unsigned int s_t;
  __threadfence();                               // release colsum write
  if (l == 0) s_t = atomicAdd(&ws->ticket, 1u);
  __syncthreads();
  if (s_t == 513u) {
    __threadfence();                             // acquire all colsum writes
    finalize_wave<INIT>(ws, l);
    if (l == 0) ws->ticket = 0u;                 // reset for next iteration
  }
}

__global__ void write_out_kernel(const float* __restrict__ mean, float* __restrict__ out)
{
  int i = threadIdx.x;
  if (i < SDIM) out[i] = mean[1 + i];
}

extern "C" void kernel_launch(void* const* d_in, const int* in_sizes, int n_in,
                              void* d_out, int out_size, void* d_ws, size_t ws_size,
                              hipStream_t stream)
{
  (void)in_sizes; (void)n_in; (void)out_size; (void)ws_size;
  const float* data = (const float*)d_in[0];
  Ws* ws = (Ws*)d_ws;

  // zero the ticket (everything else is fully overwritten each pass)
  hipMemsetAsync(d_ws, 0, 16, stream);

  // init: mean = normalize(mean over N of projected)
  big_kernel<true><<<dim3(GRID), dim3(BLK), 0, stream>>>(data, ws, 0);
  colreduce_kernel<true><<<dim3(514), dim3(64), 0, stream>>>(ws);

  for (int it = 0; it < NITER; ++it) {
    big_kernel<false><<<dim3(GRID), dim3(BLK), 0, stream>>>(data, ws, (it & 1) ^ 1);
    colreduce_kernel<false><<<dim3(514), dim3(64), 0, stream>>>(ws);
  }

  float* meanp = (float*)((char*)d_ws + offsetof(Ws, mean));
  write_out_kernel<<<dim3(1), dim3(512), 0, stream>>>(meanp, (float*)d_out);
}

// Round 6
// 7282.872 us; speedup vs baseline: 1.0378x; 1.0378x over previous
//
#include <hip/hip_runtime.h>
#include <math.h>
#include <cstddef>

#define N_PTS 131072
#define SDIM  512
#define D1    513

static constexpr int NITER = 100;
static constexpr int BLK   = 512;            // 8 waves / block
static constexpr int GRID  = 1024;           // 4 blocks / CU resident
static constexpr int WPB   = BLK / 64;       // 8 waves per block
static constexpr int NW    = GRID * WPB;     // 8192 waves
static constexpr int RPW   = N_PTS / NW;     // 16 rows per wave

struct Ws {
  double colsum[514];          // [0..511] spatial, [512] t-sum, [513] cc-sum
  double part[514][GRID];      // column-major per-block partials
  float  mean[513];            // [0] = time coordinate
};

// ---------------- streaming kernel: one row per wave, 2 float4/lane ----------------
// ~57 VGPR target -> 8 waves/SIMD (32/CU, 100% occupancy)
template<bool INIT>
__global__ __launch_bounds__(BLK, 8)
void big_kernel(const float* __restrict__ data, Ws* __restrict__ ws, int rev)
{
  const int l   = threadIdx.x & 63;
  const int wid = threadIdx.x >> 6;
  const int gw  = blockIdx.x * WPB + wid;    // 0..NW-1

  float  m0 = 0.f;
  float4 mka = {0,0,0,0}, mkb = {0,0,0,0};
  if constexpr (!INIT) {
    m0 = ws->mean[0];
    const float4* mp = (const float4*)(ws->mean + 1);
    mka = mp[l];        // cols 4l..4l+3
    mkb = mp[64 + l];   // cols 256+4l..+3
  }

  // 8 f64 accumulators per lane: cols 4l..4l+3 and 256+4l..+3
  double acc[8] = {};
  double acc_t = 0.0, acc_cc = 0.0;

  const int r0 = gw * RPW;

  float4 va, vb, na, nb;
  {
    int rr = rev ? (N_PTS - 1 - r0) : r0;
    const float4* b = (const float4*)(data + (size_t)rr * SDIM);
    va = b[l]; vb = b[64 + l];
  }

  for (int k = 0; k < RPW; ++k) {
    if (k + 1 < RPW) {
      int r  = r0 + k + 1;
      int rr = rev ? (N_PTS - 1 - r) : r;
      const float4* b = (const float4*)(data + (size_t)rr * SDIM);
      na = b[l]; nb = b[64 + l];
    } else { na = va; nb = vb; }

    // per-lane partial sums over 8 values (two short trees)
    float sqa = va.x * va.x;
    sqa = fmaf(va.y, va.y, sqa); sqa = fmaf(va.z, va.z, sqa); sqa = fmaf(va.w, va.w, sqa);
    float sqb = vb.x * vb.x;
    sqb = fmaf(vb.y, vb.y, sqb); sqb = fmaf(vb.z, vb.z, sqb); sqb = fmaf(vb.w, vb.w, sqb);
    float sq = sqa + sqb;

    float dot = 0.f;
    if constexpr (!INIT) {
      float da = va.x * mka.x;
      da = fmaf(va.y, mka.y, da); da = fmaf(va.z, mka.z, da); da = fmaf(va.w, mka.w, da);
      float db = vb.x * mkb.x;
      db = fmaf(vb.y, mkb.y, db); db = fmaf(vb.z, mkb.z, db); db = fmaf(vb.w, mkb.w, db);
      dot = da + db;
    }

    // 6-level butterfly across the full wave
    #pragma unroll
    for (int m = 1; m < 64; m <<= 1) {
      sq += __shfl_xor(sq, m);
      if constexpr (!INIT) dot += __shfl_xor(dot, m);
    }

    float t = sqrtf(1.0f + sq);
    float w;
    if constexpr (INIT) {
      w = 1.0f;
    } else {
      float a = fmaf(m0, t, -dot);        // -mdot(mean, p)
      float x = fmaxf(a, 1.0f + 1e-5f);
      float s = sqrtf(fmaf(x, x, -1.0f)); // sinh(d)
      float d = logf(x + s);              // arccosh(x)
      w = d / s;                          // d / sinh(d)
      if (l == 0) acc_cc = fma((double)w, (double)x, acc_cc);
    }
    if (l == 0) acc_t = fma((double)w, (double)t, acc_t);

    double wd = (double)w;
    acc[0] = fma(wd, (double)va.x, acc[0]);
    acc[1] = fma(wd, (double)va.y, acc[1]);
    acc[2] = fma(wd, (double)va.z, acc[2]);
    acc[3] = fma(wd, (double)va.w, acc[3]);
    acc[4] = fma(wd, (double)vb.x, acc[4]);
    acc[5] = fma(wd, (double)vb.y, acc[5]);
    acc[6] = fma(wd, (double)vb.z, acc[6]);
    acc[7] = fma(wd, (double)vb.w, acc[7]);

    va = na; vb = nb;
  }

  __shared__ double s_red[WPB][514];
  {
    int b = l * 4;
    s_red[wid][b + 0] = acc[0]; s_red[wid][b + 1] = acc[1];
    s_red[wid][b + 2] = acc[2]; s_red[wid][b + 3] = acc[3];
    s_red[wid][256 + b + 0] = acc[4]; s_red[wid][256 + b + 1] = acc[5];
    s_red[wid][256 + b + 2] = acc[6]; s_red[wid][256 + b + 3] = acc[7];
    if (l == 0) { s_red[wid][512] = acc_t; s_red[wid][513] = acc_cc; }
  }
  __syncthreads();

  for (int c = threadIdx.x; c < 514; c += BLK) {
    double s = 0.0;
    #pragma unroll
    for (int w2 = 0; w2 < WPB; ++w2) s += s_red[w2][c];
    ws->part[c][blockIdx.x] = s;
  }
}

// ---------------- per-column reduce: one wave per column ----------------
__global__ __launch_bounds__(64)
void colreduce_kernel(Ws* __restrict__ ws)
{
  const int c = blockIdx.x;       // 0..513
  const int l = threadIdx.x;
  const double* col = ws->part[c];
  double s = 0.0;
  #pragma unroll
  for (int k = 0; k < GRID / 64; ++k) s += col[l + 64 * k];
  #pragma unroll
  for (int m = 1; m < 64; m <<= 1) s += __shfl_xor(s, m);
  if (l == 0) ws->colsum[c] = s;
}

// ---------------- finalize: one wave does the exp-map update ----------------
template<bool INIT>
__global__ __launch_bounds__(64)
void finalize_kernel(Ws* __restrict__ ws)
{
  const int l = threadIdx.x;
  double sv[9];
  #pragma unroll
  for (int q = 0; q < 9; ++q) {
    int c = q * 64 + l;
    sv[q] = 0.0;
    if (c < D1) sv[q] = ws->colsum[(c == 0) ? 512 : (c - 1)];
  }

  if constexpr (INIT) {
    double r[9]; double s2 = 0.0;
    #pragma unroll
    for (int q = 0; q < 9; ++q) {
      int c = q * 64 + l;
      r[q] = 0.0;
      if (c < D1) { r[q] = sv[q] / (double)N_PTS; s2 += r[q] * r[q]; }
    }
    #pragma unroll
    for (int m = 1; m < 64; m <<= 1) s2 += __shfl_xor(s2, m);
    double r0 = __shfl(r[0], 0);
    double inv = 1.0 / sqrt(fabs(s2 - 2.0 * r0 * r0));
    #pragma unroll
    for (int q = 0; q < 9; ++q) {
      int c = q * 64 + l;
      if (c < D1) ws->mean[c] = (float)(r[q] * inv);
    }
  } else {
    double cc = ws->colsum[513];
    double mv[9], yv[9]; double sy = 0.0;
    #pragma unroll
    for (int q = 0; q < 9; ++q) {
      int c = q * 64 + l;
      mv[q] = 0.0; yv[q] = 0.0;
      if (c < D1) {
        double m = (double)ws->mean[c];
        double y = 0.02 * (sv[q] - cc * m) / (double)N_PTS;  // y = -R*g, R=0.01
        mv[q] = m; yv[q] = y;
        sy += y * y;
      }
    }
    #pragma unroll
    for (int m = 1; m < 64; m <<= 1) sy += __shfl_xor(sy, m);
    double y0 = __shfl(yv[0], 0);
    double n = sqrt(fabs(sy - 2.0 * y0 * y0));
    n = fmax(n, 1e-5);
    double ch = cosh(n);
    double sn = (n < 1e-4) ? (1.0 + n * n / 6.0) : (sinh(n) / n);
    double nm[9]; double s2 = 0.0;
    #pragma unroll
    for (int q = 0; q < 9; ++q) {
      int c = q * 64 + l;
      nm[q] = 0.0;
      if (c < D1) { nm[q] = ch * mv[q] + sn * yv[q]; s2 += nm[q] * nm[q]; }
    }
    #pragma unroll
    for (int m = 1; m < 64; m <<= 1) s2 += __shfl_xor(s2, m);
    double m0n = __shfl(nm[0], 0);
    double inv = 1.0 / sqrt(fabs(s2 - 2.0 * m0n * m0n));
    #pragma unroll
    for (int q = 0; q < 9; ++q) {
      int c = q * 64 + l;
      if (c < D1) ws->mean[c] = (float)(nm[q] * inv);
    }
  }
}

__global__ void write_out_kernel(const float* __restrict__ mean, float* __restrict__ out)
{
  int i = threadIdx.x;
  if (i < SDIM) out[i] = mean[1 + i];
}

extern "C" void kernel_launch(void* const* d_in, const int* in_sizes, int n_in,
                              void* d_out, int out_size, void* d_ws, size_t ws_size,
                              hipStream_t stream)
{
  (void)in_sizes; (void)n_in; (void)out_size; (void)ws_size;
  const float* data = (const float*)d_in[0];
  Ws* ws = (Ws*)d_ws;

  // init: mean = normalize(mean over N of projected). No memset needed:
  // part/colsum/mean are fully overwritten before any read each pass.
  big_kernel<true><<<dim3(GRID), dim3(BLK), 0, stream>>>(data, ws, 0);
  colreduce_kernel<<<dim3(514), dim3(64), 0, stream>>>(ws);
  finalize_kernel<true><<<dim3(1), dim3(64), 0, stream>>>(ws);

  for (int it = 0; it < NITER; ++it) {
    big_kernel<false><<<dim3(GRID), dim3(BLK), 0, stream>>>(data, ws, (it & 1) ^ 1);
    colreduce_kernel<<<dim3(514), dim3(64), 0, stream>>>(ws);
    finalize_kernel<false><<<dim3(1), dim3(64), 0, stream>>>(ws);
  }

  float* meanp = (float*)((char*)d_ws + offsetof(Ws, mean));
  write_out_kernel<<<dim3(1), dim3(512), 0, stream>>>(meanp, (float*)d_out);
}